// Round 6
// baseline (218.492 us; speedup 1.0000x reference)
//
#include <hip/hip_runtime.h>

// Problem constants (fixed by setup_inputs):
//   x: [B=64, D=64, H=32, W=32] fp32   -> N = B*H*W = 65536 rows of D=64
//   codebook: [K=512, D=64] fp32
// Output layout (all fp32, concatenated flat in return order):
//   [0 .. 4194304)        quant_out [B,D,H,W]
//   [4194304]             loss
//   [4194305]             perplexity
//   [4194306 .. +65536)   encoding_indice [B, H*W] (as float)
//   [4259842 .. +32768)   index_program [B,K]
//   [4292610 .. +32768)   softmax_histogram [B,K]

#define OFF_LOSS 4194304
#define OFF_PERP 4194305
#define OFF_ENC  4194306
#define OFF_IP   4259842
#define OFF_SH   4292610

// Each block: 64 rows (one 64-row slab of one batch; 16 blocks per batch).
// Thread tile: 8 rows x 16 cols.
// Scores REPLICATE the reference's fp32 expansion (this is the key):
//   t1   = fl32( ||x_r||^2 + ||e_k||^2 )     (magnitude ~64 -> ulp 7.6e-6)
//   dist = fl32( t1 - 2*dot )                (second ulp(64) quantization)
// argmin over dist with lowest-k tie-break (np.argmin first-occurrence).
// The ulp(64) grid makes exact ties common; tie-break IS the reference
// behavior we must match (true/f64 argmin provably fails: R1-R5 = 323.0).
__global__ __launch_bounds__(256) void vq_main(
    const float* __restrict__ x, const float* __restrict__ cb,
    float* __restrict__ out)
{
    __shared__ float  xs[64 * 64];     // xs[d*64 + r], transposed x tile
    __shared__ float  csT[64 * 132];   // csT[d*132 + k] for current 128-code chunk
    __shared__ float  ce2[512];        // ||e_k||^2 (fp32)
    __shared__ float  sxx[64];         // ||x_r||^2 (fp32) per row
    __shared__ int    sidx[64];        // argmin code per row

    const int t    = threadIdx.x;
    const int blk  = blockIdx.x;
    const int b    = blk >> 4;          // batch index
    const int row0 = (blk & 15) << 6;   // row offset within batch (H*W space)
    const int tr   = t >> 5;            // 0..7  (row group)
    const int tc   = t & 31;            // 0..31 (col group)

    // ---- stage x tile (coalesced: lanes sweep r for fixed d) ----
    {
        const float* xb = x + ((size_t)b << 16) + row0;   // b*D*HW
        #pragma unroll
        for (int p = 0; p < 16; ++p) {
            const int d = (p << 2) + (t >> 6);
            const int r = t & 63;
            xs[(d << 6) + r] = xb[((size_t)d << 10) + r];
        }
    }
    __syncthreads();
    // ---- ||x_r||^2 in fp32 (order-insensitive to argmin: row-uniform shift) ----
    if (t < 64) {
        float s = 0.f;
        for (int d = 0; d < 64; ++d) { const float v = xs[(d << 6) + t]; s = fmaf(v, v, s); }
        sxx[t] = s;
    }

    float acc[8][16];
    #pragma unroll
    for (int i = 0; i < 8; ++i)
        #pragma unroll
        for (int c = 0; c < 16; ++c) acc[i][c] = 0.f;

    const float4* cb4 = (const float4*)cb;

    // ---- GEMM: 4 chunks of 128 codes ----
    #pragma unroll
    for (int kc = 0; kc < 4; ++kc) {
        __syncthreads();
        #pragma unroll
        for (int p = 0; p < 8; ++p) {
            const int fi = (p << 8) + t;      // float4 index in chunk, 0..2047
            const int k  = fi >> 4;           // 0..127
            const int d4 = fi & 15;           // which float4 along D
            const float4 v = cb4[(kc << 11) + fi];   // coalesced
            csT[((d4 << 2) + 0) * 132 + k] = v.x;
            csT[((d4 << 2) + 1) * 132 + k] = v.y;
            csT[((d4 << 2) + 2) * 132 + k] = v.z;
            csT[((d4 << 2) + 3) * 132 + k] = v.w;
            float pr = v.x * v.x + v.y * v.y + v.z * v.z + v.w * v.w;
            #pragma unroll
            for (int off = 1; off < 16; off <<= 1) pr += __shfl_xor(pr, off, 16);
            if ((t & 15) == 0) ce2[(kc << 7) + k] = pr;
        }
        __syncthreads();
        for (int d = 0; d < 64; ++d) {
            const float4 a0 = *(const float4*)&xs[(d << 6) + (tr << 2)];
            const float4 a1 = *(const float4*)&xs[(d << 6) + (tr << 2) + 32];
            const float4 bq = *(const float4*)&csT[d * 132 + (tc << 2)];
            const float av[8] = {a0.x, a0.y, a0.z, a0.w, a1.x, a1.y, a1.z, a1.w};
            const float bv[4] = {bq.x, bq.y, bq.z, bq.w};
            #pragma unroll
            for (int i = 0; i < 8; ++i)
                #pragma unroll
                for (int j = 0; j < 4; ++j)
                    acc[i][(kc << 2) + j] = fmaf(av[i], bv[j], acc[i][(kc << 2) + j]);
        }
    }

    // ---- epilogue: ref-exact fp32 dist; per-row argmin + softmax(-dist) ----
    float* ip  = out + OFF_IP;
    float* enc = out + OFF_ENC;
    float invz[8];

    #pragma unroll
    for (int i = 0; i < 8; ++i) {
        const int row = ((i >> 2) << 5) + (tr << 2) + (i & 3);
        const float xxr = sxx[row];
        float m = 1e30f; int bk = 0;
        #pragma unroll
        for (int c = 0; c < 16; ++c) {
            const int k = ((c >> 2) << 7) + (tc << 2) + (c & 3);   // ascending in c
            const float t1   = xxr + ce2[k];          // fp32 round @ ulp(~64)
            const float dist = t1 - 2.f * acc[i][c];  // fp32 round @ ulp(~64)
            acc[i][c] = dist;
            if (dist < m) { m = dist; bk = k; }       // strict <: lowest k kept
        }
        // lexicographic (min dist, min k) butterfly across the 32 lanes of row
        #pragma unroll
        for (int off = 1; off < 32; off <<= 1) {
            const float mo = __shfl_xor(m, off, 32);
            const int   ko = __shfl_xor(bk, off, 32);
            if (mo < m || (mo == m && ko < bk)) { m = mo; bk = ko; }
        }
        float z = 0.f;
        #pragma unroll
        for (int c = 0; c < 16; ++c) {
            const float e = __expf(m - acc[i][c]);    // softmax(-dist), shifted
            acc[i][c] = e; z += e;
        }
        #pragma unroll
        for (int off = 1; off < 32; off <<= 1) z += __shfl_xor(z, off, 32);
        invz[i] = 1.f / z;

        if (tc == 0) {
            sidx[row] = bk;
            atomicAdd(&ip[((size_t)b << 9) + bk], 1.0f);
            enc[((size_t)b << 10) + row0 + row] = (float)bk;
        }
    }

    __syncthreads();   // all csT reads done; sidx visible

    // ---- softmax histogram: block-reduce in LDS (alias csT), then global ----
    float* shist = csT;
    float* sh    = out + OFF_SH;
    shist[t] = 0.f; shist[t + 256] = 0.f;
    __syncthreads();
    #pragma unroll
    for (int c = 0; c < 16; ++c) {
        const int k = ((c >> 2) << 7) + (tc << 2) + (c & 3);
        float cs = 0.f;
        #pragma unroll
        for (int i = 0; i < 8; ++i) cs += acc[i][c] * invz[i];
        atomicAdd(&shist[k], cs);
    }
    __syncthreads();
    atomicAdd(&sh[((size_t)b << 9) + t], shist[t]);
    atomicAdd(&sh[((size_t)b << 9) + t + 256], shist[t + 256]);

    // ---- quantized output + loss partial (from sidx) ----
    const int r = t & 63;
    const int code = sidx[r];
    float lsum = 0.f;
    #pragma unroll
    for (int p = 0; p < 16; ++p) {
        const int d = (p << 2) + (t >> 6);
        const float q = cb[(code << 6) + d];
        const float diff = q - xs[(d << 6) + r];
        lsum += diff * diff;
        out[(((size_t)(b << 6) + d) << 10) + row0 + r] = q;
    }
    #pragma unroll
    for (int off = 1; off < 64; off <<= 1) lsum += __shfl_xor(lsum, off, 64);
    if ((t & 63) == 0) atomicAdd(&out[OFF_LOSS], lsum);
}

// loss scale + perplexity from per-batch code counts
__global__ __launch_bounds__(256) void vq_final(float* __restrict__ out)
{
    __shared__ float red[4];
    const int t = threadIdx.x;
    const float* ip = out + OFF_IP;
    float h = 0.f;
    #pragma unroll
    for (int kk = 0; kk < 2; ++kk) {
        const int k = t + (kk << 8);
        float c = 0.f;
        for (int bb = 0; bb < 64; ++bb) c += ip[(bb << 9) + k];
        const float pav = c * (1.0f / 65536.f);
        h += pav * logf(pav + 1e-10f);
    }
    #pragma unroll
    for (int off = 1; off < 64; off <<= 1) h += __shfl_xor(h, off, 64);
    if ((t & 63) == 0) red[t >> 6] = h;
    __syncthreads();
    if (t == 0) {
        const float H = red[0] + red[1] + red[2] + red[3];
        out[OFF_PERP] = expf(-H);
        out[OFF_LOSS] = out[OFF_LOSS] * (1.25f / 4194304.f);
    }
}

extern "C" void kernel_launch(void* const* d_in, const int* in_sizes, int n_in,
                              void* d_out, int out_size, void* d_ws, size_t ws_size,
                              hipStream_t stream)
{
    const float* x  = (const float*)d_in[0];
    const float* cb = (const float*)d_in[1];
    float* out = (float*)d_out;
    (void)d_ws; (void)ws_size;

    // zero the atomically-accumulated regions (loss; ip+sh contiguous 65536)
    hipMemsetAsync(out + OFF_LOSS, 0, sizeof(float), stream);
    hipMemsetAsync(out + OFF_IP, 0, (size_t)65536 * sizeof(float), stream);

    vq_main<<<1024, 256, 0, stream>>>(x, cb, out);
    vq_final<<<1, 256, 0, stream>>>(out);
}

// Round 7
// 217.549 us; speedup vs baseline: 1.0043x; 1.0043x over previous
//
#include <hip/hip_runtime.h>

// Problem constants (fixed by setup_inputs):
//   x: [B=64, D=64, H=32, W=32] fp32   -> N = B*H*W = 65536 rows of D=64
//   codebook: [K=512, D=64] fp32
// Output layout (all fp32, concatenated flat in return order):
//   [0 .. 4194304)        quant_out [B,D,H,W]
//   [4194304]             loss
//   [4194305]             perplexity
//   [4194306 .. +65536)   encoding_indice [B, H*W] (as float)
//   [4259842 .. +32768)   index_program [B,K]
//   [4292610 .. +32768)   softmax_histogram [B,K]

#define OFF_LOSS 4194304
#define OFF_PERP 4194305
#define OFF_ENC  4194306
#define OFF_IP   4259842
#define OFF_SH   4292610

// Scores replicate the reference's fp32 expansion exactly (R6-proven):
//   t1   = fl32( ||x_r||^2 + ||e_k||^2 );  dist = fl32( t1 - 2*dot )
// argmin with lowest-k tie-break. Dot/ce2/sxx fmaf chains are bit-identical
// to R6 (only LDS placement/scheduling changed this round).
//
// R7 changes (perf only):
//  - csT XOR-swizzle, stride 128: store (k,d) at col' = k ^ (((d>>2)&7)<<2).
//    Transpose scatter-writes go from 8-way bank conflict to 2-way (free).
//  - Register prefetch of next chunk's codebook float4s: global loads issue
//    before the compute barrier, land during the 64-d FMA loop.
//  - float4 xs staging (4 insts instead of 16).
//  - single fused memset; vq_final widened to 512 threads + unrolled.
__global__ __launch_bounds__(256, 3) void vq_main(
    const float* __restrict__ x, const float* __restrict__ cb,
    float* __restrict__ out)
{
    __shared__ float  xs[64 * 64];     // xs[d*64 + r], transposed x tile
    __shared__ float  csT[64 * 128];   // swizzled [d][k'] for current 128-code chunk
    __shared__ float  ce2[512];        // ||e_k||^2 (fp32)
    __shared__ float  sxx[64];         // ||x_r||^2 (fp32) per row
    __shared__ int    sidx[64];        // argmin code per row

    const int t    = threadIdx.x;
    const int blk  = blockIdx.x;
    const int b    = blk >> 4;          // batch index
    const int row0 = (blk & 15) << 6;   // row offset within batch (H*W space)
    const int tr   = t >> 5;            // 0..7  (row group)
    const int tc   = t & 31;            // 0..31 (col group)

    const float4* cb4 = (const float4*)cb;

    // ---- stage x tile as float4 (lanes sweep r4: coalesced + conflict-free) ----
    {
        const float4* xb4 = (const float4*)(x + ((size_t)b << 16) + row0);
        #pragma unroll
        for (int p = 0; p < 4; ++p) {
            const int fi = (p << 8) + t;      // 0..1023
            const int d  = fi >> 4;
            const int r4 = fi & 15;
            *(float4*)&xs[(d << 6) + (r4 << 2)] = xb4[(d << 8) + r4];
        }
    }

    // ---- prefetch chunk 0 of codebook into registers ----
    float4 pv[8];
    #pragma unroll
    for (int p = 0; p < 8; ++p) pv[p] = cb4[(p << 8) + t];

    __syncthreads();
    // ---- ||x_r||^2 fp32, sequential fmaf over d (bit-exact vs R6) ----
    if (t < 64) {
        float s = 0.f;
        for (int d = 0; d < 64; ++d) { const float v = xs[(d << 6) + t]; s = fmaf(v, v, s); }
        sxx[t] = s;
    }

    float acc[8][16];
    #pragma unroll
    for (int i = 0; i < 8; ++i)
        #pragma unroll
        for (int c = 0; c < 16; ++c) acc[i][c] = 0.f;

    // ---- GEMM: 4 chunks of 128 codes ----
    #pragma unroll
    for (int kc = 0; kc < 4; ++kc) {
        __syncthreads();   // csT free (prior chunk's reads done); sxx visible
        // stage csT from registers (swizzled scatter) + ce2
        #pragma unroll
        for (int p = 0; p < 8; ++p) {
            const int fi = (p << 8) + t;      // float4 index in chunk, 0..2047
            const int k  = fi >> 4;           // 0..127
            const int d4 = fi & 15;           // which float4 along D
            const float4 v = pv[p];
            const int swz = (d4 & 7) << 2;    // == ((d>>2)&7)<<2 for d=4*d4+j
            float* base = &csT[(d4 << 9) + (k ^ swz)];   // row 4*d4, swizzled col
            base[0]   = v.x;
            base[128] = v.y;
            base[256] = v.z;
            base[384] = v.w;
            float pr = v.x * v.x + v.y * v.y + v.z * v.z + v.w * v.w;
            #pragma unroll
            for (int off = 1; off < 16; off <<= 1) pr += __shfl_xor(pr, off, 16);
            if ((t & 15) == 0) ce2[(kc << 7) + k] = pr;
        }
        // issue next chunk's global loads now; they complete during the d-loop
        if (kc < 3) {
            #pragma unroll
            for (int p = 0; p < 8; ++p) pv[p] = cb4[((kc + 1) << 11) + (p << 8) + t];
        }
        __syncthreads();   // csT ready
        #pragma unroll 2
        for (int db = 0; db < 16; ++db) {
            const int swz = (db & 7) << 2;
            const float* cbase = &csT[(db << 9) + (((tc << 2)) ^ swz)];
            #pragma unroll
            for (int j = 0; j < 4; ++j) {
                const int d = (db << 2) + j;
                const float4 a0 = *(const float4*)&xs[(d << 6) + (tr << 2)];
                const float4 a1 = *(const float4*)&xs[(d << 6) + (tr << 2) + 32];
                const float4 bq = *(const float4*)&cbase[j << 7];
                const float av[8] = {a0.x, a0.y, a0.z, a0.w, a1.x, a1.y, a1.z, a1.w};
                const float bv[4] = {bq.x, bq.y, bq.z, bq.w};
                #pragma unroll
                for (int i = 0; i < 8; ++i)
                    #pragma unroll
                    for (int jj = 0; jj < 4; ++jj)
                        acc[i][(kc << 2) + jj] = fmaf(av[i], bv[jj], acc[i][(kc << 2) + jj]);
            }
        }
    }

    // ---- epilogue: ref-exact fp32 dist; per-row argmin + softmax(-dist) ----
    float* ip  = out + OFF_IP;
    float* enc = out + OFF_ENC;
    float invz[8];

    #pragma unroll
    for (int i = 0; i < 8; ++i) {
        const int row = ((i >> 2) << 5) + (tr << 2) + (i & 3);
        const float xxr = sxx[row];
        float m = 1e30f; int bk = 0;
        #pragma unroll
        for (int c = 0; c < 16; ++c) {
            const int k = ((c >> 2) << 7) + (tc << 2) + (c & 3);   // ascending in c
            const float t1   = xxr + ce2[k];          // fp32 round @ ulp(~64)
            const float dist = t1 - 2.f * acc[i][c];  // fp32 round @ ulp(~64)
            acc[i][c] = dist;
            if (dist < m) { m = dist; bk = k; }       // strict <: lowest k kept
        }
        // lexicographic (min dist, min k) butterfly across the 32 lanes of row
        #pragma unroll
        for (int off = 1; off < 32; off <<= 1) {
            const float mo = __shfl_xor(m, off, 32);
            const int   ko = __shfl_xor(bk, off, 32);
            if (mo < m || (mo == m && ko < bk)) { m = mo; bk = ko; }
        }
        float z = 0.f;
        #pragma unroll
        for (int c = 0; c < 16; ++c) {
            const float e = __expf(m - acc[i][c]);    // softmax(-dist), shifted
            acc[i][c] = e; z += e;
        }
        #pragma unroll
        for (int off = 1; off < 32; off <<= 1) z += __shfl_xor(z, off, 32);
        invz[i] = 1.f / z;

        if (tc == 0) {
            sidx[row] = bk;
            atomicAdd(&ip[((size_t)b << 9) + bk], 1.0f);
            enc[((size_t)b << 10) + row0 + row] = (float)bk;
        }
    }

    __syncthreads();   // all csT reads done; sidx visible

    // ---- softmax histogram: block-reduce in LDS (alias csT), then global ----
    float* shist = csT;
    float* sh    = out + OFF_SH;
    shist[t] = 0.f; shist[t + 256] = 0.f;
    __syncthreads();
    #pragma unroll
    for (int c = 0; c < 16; ++c) {
        const int k = ((c >> 2) << 7) + (tc << 2) + (c & 3);
        float cs = 0.f;
        #pragma unroll
        for (int i = 0; i < 8; ++i) cs += acc[i][c] * invz[i];
        atomicAdd(&shist[k], cs);
    }
    __syncthreads();
    atomicAdd(&sh[((size_t)b << 9) + t], shist[t]);
    atomicAdd(&sh[((size_t)b << 9) + t + 256], shist[t + 256]);

    // ---- quantized output + loss partial (from sidx) ----
    const int r = t & 63;
    const int code = sidx[r];
    float lsum = 0.f;
    #pragma unroll
    for (int p = 0; p < 16; ++p) {
        const int d = (p << 2) + (t >> 6);
        const float q = cb[(code << 6) + d];
        const float diff = q - xs[(d << 6) + r];
        lsum += diff * diff;
        out[(((size_t)(b << 6) + d) << 10) + row0 + r] = q;
    }
    #pragma unroll
    for (int off = 1; off < 64; off <<= 1) lsum += __shfl_xor(lsum, off, 64);
    if ((t & 63) == 0) atomicAdd(&out[OFF_LOSS], lsum);
}

// loss scale + perplexity from per-batch code counts (512 threads, one k each)
__global__ __launch_bounds__(512) void vq_final(float* __restrict__ out)
{
    __shared__ float red[8];
    const int t = threadIdx.x;
    const float* ip = out + OFF_IP;
    float c0 = 0.f, c1 = 0.f, c2 = 0.f, c3 = 0.f;
    #pragma unroll
    for (int bb = 0; bb < 64; bb += 4) {
        c0 += ip[((bb + 0) << 9) + t];
        c1 += ip[((bb + 1) << 9) + t];
        c2 += ip[((bb + 2) << 9) + t];
        c3 += ip[((bb + 3) << 9) + t];
    }
    const float c = (c0 + c1) + (c2 + c3);
    const float pav = c * (1.0f / 65536.f);
    float h = pav * logf(pav + 1e-10f);
    #pragma unroll
    for (int off = 1; off < 64; off <<= 1) h += __shfl_xor(h, off, 64);
    if ((t & 63) == 0) red[t >> 6] = h;
    __syncthreads();
    if (t == 0) {
        float H = 0.f;
        #pragma unroll
        for (int w = 0; w < 8; ++w) H += red[w];
        out[OFF_PERP] = expf(-H);
        out[OFF_LOSS] = out[OFF_LOSS] * (1.25f / 4194304.f);
    }
}

extern "C" void kernel_launch(void* const* d_in, const int* in_sizes, int n_in,
                              void* d_out, int out_size, void* d_ws, size_t ws_size,
                              hipStream_t stream)
{
    const float* x  = (const float*)d_in[0];
    const float* cb = (const float*)d_in[1];
    float* out = (float*)d_out;
    (void)d_ws; (void)ws_size;

    // single memset: zero [loss, perp, enc, ip, sh] = tail 131074 floats.
    // enc is fully overwritten non-atomically; loss/ip/sh need the zeros.
    hipMemsetAsync(out + OFF_LOSS, 0, (size_t)131074 * sizeof(float), stream);

    vq_main<<<1024, 256, 0, stream>>>(x, cb, out);
    vq_final<<<1, 512, 0, stream>>>(out);
}